// Round 14
// baseline (128.518 us; speedup 1.0000x reference)
//
#include <hip/hip_runtime.h>
#include <hip/hip_bf16.h>

typedef unsigned short u16;
typedef __attribute__((ext_vector_type(8))) short bf16x8;
typedef __attribute__((ext_vector_type(4))) float f32x4;
typedef __attribute__((ext_vector_type(4))) unsigned short u16x4;

#define SQ 4096
#define HQ 128
#define NCHUNK 144   // per batch: sum over qt2 of ceil((qt2+1)/4), chunk = 8 key-tiles

__device__ __forceinline__ u16 f2b(float f) {
  unsigned int u = __float_as_uint(f);
  unsigned int r = (u + 0x7fffu + ((u >> 16) & 1u)) >> 16;  // RNE bf16
  return (u16)r;
}

__device__ __forceinline__ u16 f2b_fast(float f) {
  __hip_bfloat16 h = __float2bfloat16(f);
  return __builtin_bit_cast(u16, h);
}

__device__ __forceinline__ float b2f(u16 v) {
  unsigned int u = ((unsigned int)v) << 16;
  return __uint_as_float(u);
}

__device__ __forceinline__ void gload_lds16(const void* gsrc, void* ldst) {
  __builtin_amdgcn_global_load_lds((const __attribute__((address_space(1))) void*)gsrc,
                                   (__attribute__((address_space(3))) void*)ldst, 16, 0, 0);
}

// Wt[z][n][k] = W_z[k][n]  (bf16, B^T layout for MFMA B-frags)
__global__ __launch_bounds__(256) void k_wt(const float* __restrict__ Wq, const float* __restrict__ Wk,
                                            const float* __restrict__ Wv, u16* __restrict__ wt) {
  int idx = blockIdx.x * 256 + threadIdx.x;
  int z = idx >> 17, r = idx & 131071, n = r >> 10, k = r & 1023;
  const float* W = (z == 0) ? Wq : (z == 1) ? Wk : Wv;
  wt[idx] = f2b(W[k * 128 + n]);
}

// Fused conv+proj v7 (TLP-first): tile 32 rows x 192 cols, grid (512,2) = 1024
// blocks of 256 thr (4 waves 1m x 4n, wave = 32x48, 6 MFMA/iter). LDS 32 KB ->
// 4 blocks/CU resident = 16 waves/CU (4 independent barrier domains cover the
// per-iter staging latency). A staged f32 via global_load_lds (async), cvt at
// frag-load; B bf16 via global_load_lds. Both dbuf, 1 barrier/iter.
__global__ __launch_bounds__(256, 4) void k_proj(const float* __restrict__ x, const u16* __restrict__ wt,
                                                 u16* __restrict__ qb, u16* __restrict__ kb,
                                                 u16* __restrict__ vt) {
  int mt = blockIdx.x, nh = blockIdx.y;
  int t = threadIdx.x;
  int wn = t >> 6, lane = t & 63;
  int lr = lane & 15, lg = lane >> 4;

  __shared__ __align__(16) float Al[2][32 * 32];   // 2 x 4 KB (f32)
  __shared__ __align__(16) u16 Bl[2][192 * 32];    // 2 x 12 KB (bf16)

  f32x4 acc[2][3];
#pragma unroll
  for (int i = 0; i < 2; ++i)
#pragma unroll
    for (int j = 0; j < 3; ++j) acc[i][j] = (f32x4){0.f, 0.f, 0.f, 0.f};

  const float* xbase = x + (long)(mt * 32) * 1024;
  const u16* wbase = wt + (long)(nh * 192) * 1024;

  // A stage: 256 16B chunks (32 rows x 8 f32-chunks), 1/thread
  auto stage_a = [&](int bufi, int k0) {
    int row = t >> 3, ch = t & 7;
    gload_lds16(xbase + (long)row * 1024 + k0 + ((ch ^ (row & 7)) << 2),
                &Al[bufi][0] + t * 4);
  };
  // B stage: 768 16B chunks (192 rows x 4 chunks), 3/thread
  auto stage_b = [&](int bufi, int k0) {
#pragma unroll
    for (int i = 0; i < 3; ++i) {
      int ci = i * 256 + t;
      int row = ci >> 2, ch = ci & 3;
      gload_lds16(wbase + (long)row * 1024 + k0 + ((ch ^ ((row >> 1) & 3)) << 3),
                  &Bl[bufi][0] + ci * 8);
    }
  };

  stage_a(0, 0);
  stage_b(0, 0);
  __syncthreads();

  for (int ks = 0; ks < 32; ++ks) {
    int cur = ks & 1;
    if (ks + 1 < 32) {                       // async prefetch next K-step
      stage_a(cur ^ 1, (ks + 1) * 32);
      stage_b(cur ^ 1, (ks + 1) * 32);
    }
    bf16x8 af[2], bfr[3];
#pragma unroll
    for (int i = 0; i < 2; ++i) {
      int row = i * 16 + lr;
      const float* Ap = &Al[cur][row * 32];
      int sz = row & 7;
      float4 fa = *(const float4*)(Ap + (((2 * lg) ^ sz) << 2));
      float4 fb = *(const float4*)(Ap + (((2 * lg + 1) ^ sz) << 2));
      bf16x8 v;
      v[0] = (short)f2b_fast(fa.x); v[1] = (short)f2b_fast(fa.y);
      v[2] = (short)f2b_fast(fa.z); v[3] = (short)f2b_fast(fa.w);
      v[4] = (short)f2b_fast(fb.x); v[5] = (short)f2b_fast(fb.y);
      v[6] = (short)f2b_fast(fb.z); v[7] = (short)f2b_fast(fb.w);
      af[i] = v;
    }
#pragma unroll
    for (int j = 0; j < 3; ++j) {
      int row = wn * 48 + j * 16 + lr;
      bfr[j] = *(const bf16x8*)(&Bl[cur][0] + row * 32 + ((lg ^ ((row >> 1) & 3)) << 3));
    }
#pragma unroll
    for (int i = 0; i < 2; ++i)
#pragma unroll
      for (int j = 0; j < 3; ++j)
        acc[i][j] = __builtin_amdgcn_mfma_f32_16x16x32_bf16(af[i], bfr[j], acc[i][j], 0, 0, 0);
    __syncthreads();                         // drains prefetch + gates buffer swap
  }

  // epilogue: C layout row=(lane>>4)*4+reg, col=lane&15
#pragma unroll
  for (int i = 0; i < 2; ++i)
#pragma unroll
    for (int j = 0; j < 3; ++j)
#pragma unroll
      for (int r = 0; r < 4; ++r) {
        int m = mt * 32 + i * 16 + lg * 4 + r;
        int col = nh * 192 + wn * 48 + j * 16 + lr;
        int z = col >> 7, cz = col & 127;
        u16 v = f2b(acc[i][j][r]);
        if (z == 0) qb[(long)m * 128 + cz] = v;
        else if (z == 1) kb[(long)m * 128 + cz] = v;
        else { int bb = m >> 12, sR = m & 4095; vt[(long)bb * 524288 + (long)cz * 4096 + sR] = v; }
      }
}

// flash attention v6 (R11/R13 exact, best measured ~54us): uniform split-K
// chunks (8 key-tiles each); 576 blocks. 8-wave blocks share K/V staging,
// QBLK=128, KVBLK=64, double-buffered, fixed-max softmax, ones-MFMA row-sum,
// bf16 partials.
__global__ __launch_bounds__(512, 4) void k_attn(const u16* __restrict__ qb, const u16* __restrict__ kb,
                                                 const u16* __restrict__ vt, const int* __restrict__ kmask,
                                                 u16* __restrict__ po, float* __restrict__ pl) {
  const float SCALE_LOG2 = 0.08838834764831845f * 1.4426950408889634f;
  const float MFIX = 24.0f;
  int f = (NCHUNK - 1) - (int)blockIdx.x;  // long chunks (big qt2) first
  int b = blockIdx.y;
  // decode f -> (qt2, kc): nch(q) = ceil((q+1)/4) = (q+4)>>2
  int qt2 = 0, cum = 0;
  while (cum + ((qt2 + 4) >> 2) <= f) { cum += (qt2 + 4) >> 2; ++qt2; }
  int kc = f - cum;
  int ntile = 2 * qt2 + 2;
  int kt0 = kc * 8;
  int kt1 = min(kt0 + 8, ntile);

  int t = threadIdx.x, w = t >> 6, lane = t & 63;
  int lr = lane & 15, lg = lane >> 4, sw = lr & 7;
  int qrow0 = qt2 * 128 + w * 16;
  const u16* Q = qb + ((long)(b * SQ + qrow0)) * HQ;
  const u16* K = kb + (long)b * SQ * HQ;
  const u16* V = vt + (long)b * HQ * SQ;   // V^T: [128][SQ]
  const int* msk = kmask + b * SQ;

  __shared__ __align__(16) u16 Kl[2][64 * 128];   // 2 x 16 KB
  __shared__ __align__(16) u16 Vl[2][128 * 64];   // 2 x 16 KB
  __shared__ __align__(16) u16 plds[8][16 * 64];  // 16 KB, XOR-chunk layout

  bf16x8 aq[4];
#pragma unroll
  for (int c = 0; c < 4; ++c) aq[c] = *(const bf16x8*)(Q + lr * HQ + c * 32 + lg * 8);

  bf16x8 ones;
#pragma unroll
  for (int e = 0; e < 8; ++e) ones[e] = (short)0x3F80;

  f32x4 o[8];
#pragma unroll
  for (int n = 0; n < 8; ++n) o[n] = (f32x4){0.f, 0.f, 0.f, 0.f};
  f32x4 l_acc = (f32x4){0.f, 0.f, 0.f, 0.f};

  auto stage = [&](int bufi, int kb0) {
    const u16* Kg = K + (long)kb0 * HQ;
    const u16* Vg = V + kb0;
#pragma unroll
    for (int i = 0; i < 2; ++i) {
      int ci = w * 2 + i;
      int o16 = ci * 64 + lane;
      int row = o16 >> 4, ch = o16 & 15;
      gload_lds16(Kg + row * HQ + ((ch ^ (row & 7)) << 3), &Kl[bufi][ci * 512]);
    }
#pragma unroll
    for (int i = 0; i < 2; ++i) {
      int ci = w * 2 + i;
      int o16 = ci * 64 + lane;
      int row = o16 >> 3, ch = o16 & 7;
      gload_lds16(Vg + (long)row * SQ + ((ch ^ (row & 7)) << 3), &Vl[bufi][ci * 512]);
    }
  };

  stage(0, kt0 * 64);
  __syncthreads();

  u16* pw = &plds[w][0];
  for (int kt = kt0; kt < kt1; ++kt) {
    int cur = (kt - kt0) & 1;
    int kb0 = kt * 64;
    if (kt + 1 < kt1) stage(cur ^ 1, kb0 + 64);

    if (kb0 <= qrow0 + 15) {                 // wave-uniform: any valid keys?
      f32x4 s[4];
#pragma unroll
      for (int h = 0; h < 4; ++h) {
        f32x4 acc = (f32x4){0.f, 0.f, 0.f, 0.f};
        const u16* Kp = &Kl[cur][(h * 16 + lr) * 128];
#pragma unroll
        for (int c = 0; c < 4; ++c) {
          bf16x8 bk = *(const bf16x8*)(Kp + (((c * 4 + lg) ^ sw) << 3));
          acc = __builtin_amdgcn_mfma_f32_16x16x32_bf16(aq[c], bk, acc, 0, 0, 0);
        }
        s[h] = acc;
      }
      float mf[4];
#pragma unroll
      for (int h = 0; h < 4; ++h) mf[h] = (msk[kb0 + h * 16 + lr] != 0) ? 1.0f : 0.0f;
      bool needc = (kb0 + 63 > qrow0);       // tile crosses diagonal for this wave
#pragma unroll
      for (int r = 0; r < 4; ++r) {
        int row = lg * 4 + r;
        int qr = qrow0 + row;
#pragma unroll
        for (int h = 0; h < 4; ++h) {
          float p = __builtin_exp2f(fmaf(s[h][r], SCALE_LOG2, -MFIX)) * mf[h];
          if (needc) p = ((kb0 + h * 16 + lr) <= qr) ? p : 0.0f;
          int poff = row * 64 + ((((h * 2 + (lr >> 3)) ^ (row & 7))) << 3) + (lr & 7);
          pw[poff] = f2b_fast(p);
        }
      }
      bf16x8 ap0 = *(const bf16x8*)(pw + lr * 64 + ((lg ^ sw) << 3));
      bf16x8 ap1 = *(const bf16x8*)(pw + lr * 64 + (((4 + lg) ^ sw) << 3));
      l_acc = __builtin_amdgcn_mfma_f32_16x16x32_bf16(ap0, ones, l_acc, 0, 0, 0);
      l_acc = __builtin_amdgcn_mfma_f32_16x16x32_bf16(ap1, ones, l_acc, 0, 0, 0);
#pragma unroll
      for (int n = 0; n < 8; ++n) {
        const u16* Vp = &Vl[cur][(n * 16 + lr) * 64];
        bf16x8 bv0 = *(const bf16x8*)(Vp + ((lg ^ sw) << 3));
        bf16x8 bv1 = *(const bf16x8*)(Vp + (((4 + lg) ^ sw) << 3));
        o[n] = __builtin_amdgcn_mfma_f32_16x16x32_bf16(ap0, bv0, o[n], 0, 0, 0);
        o[n] = __builtin_amdgcn_mfma_f32_16x16x32_bf16(ap1, bv1, o[n], 0, 0, 0);
      }
    }
    __syncthreads();
  }

  // ---- write partials (bf16 O, f32 l)
  long p = (long)b * NCHUNK + f;
  u16* pob = po + p * 16384;  // [128][128] bf16
#pragma unroll
  for (int n = 0; n < 8; ++n)
#pragma unroll
    for (int r = 0; r < 4; ++r)
      pob[(w * 16 + lg * 4 + r) * 128 + n * 16 + lr] = f2b_fast(o[n][r]);
  if (lr == 0) {
#pragma unroll
    for (int r = 0; r < 4; ++r) pl[p * 128 + w * 16 + lg * 4 + r] = l_acc[r];
  }
}

// merge: out[b, qt2*128+row, :] = sum_i po[i] / sum_i pl[i]
__global__ __launch_bounds__(256) void k_merge(const u16* __restrict__ po, const float* __restrict__ pl,
                                               float* __restrict__ out) {
  int qt2 = blockIdx.x, b = blockIdx.y;
  int nch = (qt2 + 4) >> 2;
  int pre = 0;
  for (int q = 0; q < qt2; ++q) pre += (q + 4) >> 2;
  long pbase = (long)b * NCHUNK + pre;
  int t = threadIdx.x;
  int row = t >> 1, c0 = (t & 1) * 64;
  float l = 0.f;
  for (int i = 0; i < nch; ++i) l += pl[(pbase + i) * 128 + row];
  float inv = 1.0f / l;
  const u16* p0 = po + pbase * 16384 + row * 128 + c0;
  float* orow = out + ((long)(b * SQ + qt2 * 128 + row)) * HQ + c0;
#pragma unroll
  for (int j = 0; j < 64; j += 4) {
    float acc0 = 0.f, acc1 = 0.f, acc2 = 0.f, acc3 = 0.f;
    for (int i = 0; i < nch; ++i) {
      u16x4 v = *(const u16x4*)(p0 + (long)i * 16384 + j);
      acc0 += b2f(v[0]); acc1 += b2f(v[1]); acc2 += b2f(v[2]); acc3 += b2f(v[3]);
    }
    float4 r = {acc0 * inv, acc1 * inv, acc2 * inv, acc3 * inv};
    *(float4*)(orow + j) = r;
  }
}

extern "C" void kernel_launch(void* const* d_in, const int* in_sizes, int n_in,
                              void* d_out, int out_size, void* d_ws, size_t ws_size,
                              hipStream_t stream) {
  const float* x  = (const float*)d_in[0];
  const float* Wq = (const float*)d_in[1];
  const float* Wk = (const float*)d_in[2];
  const float* Wv = (const float*)d_in[3];
  const int* kmask = (const int*)d_in[4];
  char* ws = (char*)d_ws;
  u16* wt = (u16*)(ws + 33554432);            // 768 KB: Wt (dead after k_proj)
  u16* qb = (u16*)(ws + 34340864);            // 4 MB: Q bf16
  u16* kb = (u16*)(ws + 38535168);            // 4 MB: K bf16
  u16* vt = (u16*)(ws + 42729472);            // 4 MB: V^T bf16 [4][128][4096]
  u16* po = (u16*)ws;                         // 18.9 MB partial O (bf16)
  float* pl = (float*)(ws + 31195136);        // 295 KB partial l (po-region tail)
  float* out = (float*)d_out;

  k_wt<<<1536, 256, 0, stream>>>(Wq, Wk, Wv, wt);
  k_proj<<<dim3(512, 2), 256, 0, stream>>>(x, wt, qb, kb, vt);
  k_attn<<<dim3(NCHUNK, 4), 512, 0, stream>>>(qb, kb, vt, kmask, po, pl);
  k_merge<<<dim3(32, 4), 256, 0, stream>>>(po, pl, out);
}

// Round 15
// 128.445 us; speedup vs baseline: 1.0006x; 1.0006x over previous
//
#include <hip/hip_runtime.h>
#include <hip/hip_bf16.h>

typedef unsigned short u16;
typedef __attribute__((ext_vector_type(8))) short bf16x8;
typedef __attribute__((ext_vector_type(4))) float f32x4;
typedef __attribute__((ext_vector_type(4))) unsigned short u16x4;

#define SQ 4096
#define HQ 128
#define NCHUNK 144   // per batch: sum over qt2 of ceil((qt2+1)/4), chunk = 8 key-tiles

__device__ __forceinline__ u16 f2b(float f) {
  unsigned int u = __float_as_uint(f);
  unsigned int r = (u + 0x7fffu + ((u >> 16) & 1u)) >> 16;  // RNE bf16
  return (u16)r;
}

__device__ __forceinline__ u16 f2b_fast(float f) {
  __hip_bfloat16 h = __float2bfloat16(f);
  return __builtin_bit_cast(u16, h);
}

__device__ __forceinline__ float b2f(u16 v) {
  unsigned int u = ((unsigned int)v) << 16;
  return __uint_as_float(u);
}

__device__ __forceinline__ void gload_lds16(const void* gsrc, void* ldst) {
  __builtin_amdgcn_global_load_lds((const __attribute__((address_space(1))) void*)gsrc,
                                   (__attribute__((address_space(3))) void*)ldst, 16, 0, 0);
}

// Wt[z][n][k] = W_z[k][n]  (bf16, B^T layout for MFMA B-frags)
__global__ __launch_bounds__(256) void k_wt(const float* __restrict__ Wq, const float* __restrict__ Wk,
                                            const float* __restrict__ Wv, u16* __restrict__ wt) {
  int idx = blockIdx.x * 256 + threadIdx.x;
  int z = idx >> 17, r = idx & 131071, n = r >> 10, k = r & 1023;
  const float* W = (z == 0) ? Wq : (z == 1) ? Wk : Wv;
  wt[idx] = f2b(W[k * 128 + n]);
}

// Fused conv+proj v8 (T3/T4 counted-vmcnt): block = 64 rows x 384 cols (all
// heads), 512 thr (8 waves 2m x 4n, wave = 32x96, 12 MFMA/iter). 4-buffer LDS
// rotation, 3-deep prefetch, raw s_barrier + counted s_waitcnt vmcnt(8) (never
// 0 in main loop) -- stage loads stay in flight ACROSS barriers. A staged f32
// from x (cvt at frag-load), B bf16 from Wt. 128 KB LDS, grid 256 (1/CU).
__global__ __launch_bounds__(512) void k_proj(const float* __restrict__ x, const u16* __restrict__ wt,
                                              u16* __restrict__ qb, u16* __restrict__ kb,
                                              u16* __restrict__ vt) {
  int mt = blockIdx.x;
  int t = threadIdx.x;
  int w = t >> 6, lane = t & 63;
  int wm = w >> 2, wn = w & 3;
  int lr = lane & 15, lg = lane >> 4;

  __shared__ __align__(16) float Al[4][64 * 32];   // 4 x 8 KB (f32)
  __shared__ __align__(16) u16 Bl[4][384 * 32];    // 4 x 24 KB (bf16)

  f32x4 acc[2][6];
#pragma unroll
  for (int i = 0; i < 2; ++i)
#pragma unroll
    for (int j = 0; j < 6; ++j) acc[i][j] = (f32x4){0.f, 0.f, 0.f, 0.f};

  const float* xbase = x + (long)(mt * 64) * 1024;

  // stage: A 512 chunks (64 rows x 8 f32-chunks) + B 1536 chunks (384 rows x 4)
  // = 2048 chunks, 4 per thread (uniform) -> 4 VMEM instr/wave/stage.
  auto stagep = [&](int bufi, int k0) {
    {
      int ci = t;                            // A chunk 0..511
      int row = ci >> 3, ch = ci & 7;
      gload_lds16(xbase + (long)row * 1024 + k0 + ((ch ^ (row & 7)) << 2),
                  &Al[bufi][0] + ci * 4);
    }
#pragma unroll
    for (int i = 0; i < 3; ++i) {
      int ci = i * 512 + t;                  // B chunk 0..1535
      int row = ci >> 2, ch = ci & 3;
      gload_lds16(wt + (long)row * 1024 + k0 + ((ch ^ ((row >> 1) & 3)) << 3),
                  &Bl[bufi][0] + ci * 8);
    }
  };

  auto compute = [&](int bufi) {
    bf16x8 af[2], bfr[6];
#pragma unroll
    for (int i = 0; i < 2; ++i) {
      int row = wm * 32 + i * 16 + lr;
      const float* Ap = &Al[bufi][row * 32];
      int sz = row & 7;
      float4 fa = *(const float4*)(Ap + (((2 * lg) ^ sz) << 2));
      float4 fb = *(const float4*)(Ap + (((2 * lg + 1) ^ sz) << 2));
      bf16x8 v;
      v[0] = (short)f2b_fast(fa.x); v[1] = (short)f2b_fast(fa.y);
      v[2] = (short)f2b_fast(fa.z); v[3] = (short)f2b_fast(fa.w);
      v[4] = (short)f2b_fast(fb.x); v[5] = (short)f2b_fast(fb.y);
      v[6] = (short)f2b_fast(fb.z); v[7] = (short)f2b_fast(fb.w);
      af[i] = v;
    }
#pragma unroll
    for (int j = 0; j < 6; ++j) {
      int row = wn * 96 + j * 16 + lr;
      bfr[j] = *(const bf16x8*)(&Bl[bufi][0] + row * 32 + ((lg ^ ((row >> 1) & 3)) << 3));
    }
#pragma unroll
    for (int i = 0; i < 2; ++i)
#pragma unroll
      for (int j = 0; j < 6; ++j)
        acc[i][j] = __builtin_amdgcn_mfma_f32_16x16x32_bf16(af[i], bfr[j], acc[i][j], 0, 0, 0);
  };

  // prologue: 3 stages in flight (12 VMEM instrs/wave)
  stagep(0, 0);
  stagep(1, 32);
  stagep(2, 64);

  for (int ks = 0; ks < 30; ++ks) {
    asm volatile("s_waitcnt vmcnt(8)" ::: "memory");   // own stage-ks landed; 2 stages stay in flight
    __builtin_amdgcn_s_barrier();                      // all waves' stage-ks landed; iter ks-1 reads done
    if (ks + 3 < 32) stagep((ks + 3) & 3, (ks + 3) * 32);
    compute(ks & 3);
  }
  asm volatile("s_waitcnt vmcnt(4)" ::: "memory");     // ks=30
  __builtin_amdgcn_s_barrier();
  compute(30 & 3);
  asm volatile("s_waitcnt vmcnt(0)" ::: "memory");     // ks=31
  __builtin_amdgcn_s_barrier();
  compute(31 & 3);

  // epilogue: C layout row=(lane>>4)*4+reg, col=lane&15
#pragma unroll
  for (int i = 0; i < 2; ++i)
#pragma unroll
    for (int j = 0; j < 6; ++j)
#pragma unroll
      for (int r = 0; r < 4; ++r) {
        int m = mt * 64 + wm * 32 + i * 16 + lg * 4 + r;
        int col = wn * 96 + j * 16 + lr;
        int z = col >> 7, cz = col & 127;
        u16 v = f2b(acc[i][j][r]);
        if (z == 0) qb[(long)m * 128 + cz] = v;
        else if (z == 1) kb[(long)m * 128 + cz] = v;
        else { int bb = m >> 12, sR = m & 4095; vt[(long)bb * 524288 + (long)cz * 4096 + sR] = v; }
      }
}

// flash attention v6 (R11/R13 exact, best measured ~54us): uniform split-K
// chunks (8 key-tiles each); 576 blocks. 8-wave blocks share K/V staging,
// QBLK=128, KVBLK=64, double-buffered, fixed-max softmax, ones-MFMA row-sum,
// bf16 partials.
__global__ __launch_bounds__(512, 4) void k_attn(const u16* __restrict__ qb, const u16* __restrict__ kb,
                                                 const u16* __restrict__ vt, const int* __restrict__ kmask,
                                                 u16* __restrict__ po, float* __restrict__ pl) {
  const float SCALE_LOG2 = 0.08838834764831845f * 1.4426950408889634f;
  const float MFIX = 24.0f;
  int f = (NCHUNK - 1) - (int)blockIdx.x;  // long chunks (big qt2) first
  int b = blockIdx.y;
  // decode f -> (qt2, kc): nch(q) = ceil((q+1)/4) = (q+4)>>2
  int qt2 = 0, cum = 0;
  while (cum + ((qt2 + 4) >> 2) <= f) { cum += (qt2 + 4) >> 2; ++qt2; }
  int kc = f - cum;
  int ntile = 2 * qt2 + 2;
  int kt0 = kc * 8;
  int kt1 = min(kt0 + 8, ntile);

  int t = threadIdx.x, w = t >> 6, lane = t & 63;
  int lr = lane & 15, lg = lane >> 4, sw = lr & 7;
  int qrow0 = qt2 * 128 + w * 16;
  const u16* Q = qb + ((long)(b * SQ + qrow0)) * HQ;
  const u16* K = kb + (long)b * SQ * HQ;
  const u16* V = vt + (long)b * HQ * SQ;   // V^T: [128][SQ]
  const int* msk = kmask + b * SQ;

  __shared__ __align__(16) u16 Kl[2][64 * 128];   // 2 x 16 KB
  __shared__ __align__(16) u16 Vl[2][128 * 64];   // 2 x 16 KB
  __shared__ __align__(16) u16 plds[8][16 * 64];  // 16 KB, XOR-chunk layout

  bf16x8 aq[4];
#pragma unroll
  for (int c = 0; c < 4; ++c) aq[c] = *(const bf16x8*)(Q + lr * HQ + c * 32 + lg * 8);

  bf16x8 ones;
#pragma unroll
  for (int e = 0; e < 8; ++e) ones[e] = (short)0x3F80;

  f32x4 o[8];
#pragma unroll
  for (int n = 0; n < 8; ++n) o[n] = (f32x4){0.f, 0.f, 0.f, 0.f};
  f32x4 l_acc = (f32x4){0.f, 0.f, 0.f, 0.f};

  auto stage = [&](int bufi, int kb0) {
    const u16* Kg = K + (long)kb0 * HQ;
    const u16* Vg = V + kb0;
#pragma unroll
    for (int i = 0; i < 2; ++i) {
      int ci = w * 2 + i;
      int o16 = ci * 64 + lane;
      int row = o16 >> 4, ch = o16 & 15;
      gload_lds16(Kg + row * HQ + ((ch ^ (row & 7)) << 3), &Kl[bufi][ci * 512]);
    }
#pragma unroll
    for (int i = 0; i < 2; ++i) {
      int ci = w * 2 + i;
      int o16 = ci * 64 + lane;
      int row = o16 >> 3, ch = o16 & 7;
      gload_lds16(Vg + (long)row * SQ + ((ch ^ (row & 7)) << 3), &Vl[bufi][ci * 512]);
    }
  };

  stage(0, kt0 * 64);
  __syncthreads();

  u16* pw = &plds[w][0];
  for (int kt = kt0; kt < kt1; ++kt) {
    int cur = (kt - kt0) & 1;
    int kb0 = kt * 64;
    if (kt + 1 < kt1) stage(cur ^ 1, kb0 + 64);

    if (kb0 <= qrow0 + 15) {                 // wave-uniform: any valid keys?
      f32x4 s[4];
#pragma unroll
      for (int h = 0; h < 4; ++h) {
        f32x4 acc = (f32x4){0.f, 0.f, 0.f, 0.f};
        const u16* Kp = &Kl[cur][(h * 16 + lr) * 128];
#pragma unroll
        for (int c = 0; c < 4; ++c) {
          bf16x8 bk = *(const bf16x8*)(Kp + (((c * 4 + lg) ^ sw) << 3));
          acc = __builtin_amdgcn_mfma_f32_16x16x32_bf16(aq[c], bk, acc, 0, 0, 0);
        }
        s[h] = acc;
      }
      float mf[4];
#pragma unroll
      for (int h = 0; h < 4; ++h) mf[h] = (msk[kb0 + h * 16 + lr] != 0) ? 1.0f : 0.0f;
      bool needc = (kb0 + 63 > qrow0);       // tile crosses diagonal for this wave
#pragma unroll
      for (int r = 0; r < 4; ++r) {
        int row = lg * 4 + r;
        int qr = qrow0 + row;
#pragma unroll
        for (int h = 0; h < 4; ++h) {
          float p = __builtin_exp2f(fmaf(s[h][r], SCALE_LOG2, -MFIX)) * mf[h];
          if (needc) p = ((kb0 + h * 16 + lr) <= qr) ? p : 0.0f;
          int poff = row * 64 + ((((h * 2 + (lr >> 3)) ^ (row & 7))) << 3) + (lr & 7);
          pw[poff] = f2b_fast(p);
        }
      }
      bf16x8 ap0 = *(const bf16x8*)(pw + lr * 64 + ((lg ^ sw) << 3));
      bf16x8 ap1 = *(const bf16x8*)(pw + lr * 64 + (((4 + lg) ^ sw) << 3));
      l_acc = __builtin_amdgcn_mfma_f32_16x16x32_bf16(ap0, ones, l_acc, 0, 0, 0);
      l_acc = __builtin_amdgcn_mfma_f32_16x16x32_bf16(ap1, ones, l_acc, 0, 0, 0);
#pragma unroll
      for (int n = 0; n < 8; ++n) {
        const u16* Vp = &Vl[cur][(n * 16 + lr) * 64];
        bf16x8 bv0 = *(const bf16x8*)(Vp + ((lg ^ sw) << 3));
        bf16x8 bv1 = *(const bf16x8*)(Vp + (((4 + lg) ^ sw) << 3));
        o[n] = __builtin_amdgcn_mfma_f32_16x16x32_bf16(ap0, bv0, o[n], 0, 0, 0);
        o[n] = __builtin_amdgcn_mfma_f32_16x16x32_bf16(ap1, bv1, o[n], 0, 0, 0);
      }
    }
    __syncthreads();
  }

  // ---- write partials (bf16 O, f32 l)
  long p = (long)b * NCHUNK + f;
  u16* pob = po + p * 16384;  // [128][128] bf16
#pragma unroll
  for (int n = 0; n < 8; ++n)
#pragma unroll
    for (int r = 0; r < 4; ++r)
      pob[(w * 16 + lg * 4 + r) * 128 + n * 16 + lr] = f2b_fast(o[n][r]);
  if (lr == 0) {
#pragma unroll
    for (int r = 0; r < 4; ++r) pl[p * 128 + w * 16 + lg * 4 + r] = l_acc[r];
  }
}

// merge: out[b, qt2*128+row, :] = sum_i po[i] / sum_i pl[i]
__global__ __launch_bounds__(256) void k_merge(const u16* __restrict__ po, const float* __restrict__ pl,
                                               float* __restrict__ out) {
  int qt2 = blockIdx.x, b = blockIdx.y;
  int nch = (qt2 + 4) >> 2;
  int pre = 0;
  for (int q = 0; q < qt2; ++q) pre += (q + 4) >> 2;
  long pbase = (long)b * NCHUNK + pre;
  int t = threadIdx.x;
  int row = t >> 1, c0 = (t & 1) * 64;
  float l = 0.f;
  for (int i = 0; i < nch; ++i) l += pl[(pbase + i) * 128 + row];
  float inv = 1.0f / l;
  const u16* p0 = po + pbase * 16384 + row * 128 + c0;
  float* orow = out + ((long)(b * SQ + qt2 * 128 + row)) * HQ + c0;
#pragma unroll
  for (int j = 0; j < 64; j += 4) {
    float acc0 = 0.f, acc1 = 0.f, acc2 = 0.f, acc3 = 0.f;
    for (int i = 0; i < nch; ++i) {
      u16x4 v = *(const u16x4*)(p0 + (long)i * 16384 + j);
      acc0 += b2f(v[0]); acc1 += b2f(v[1]); acc2 += b2f(v[2]); acc3 += b2f(v[3]);
    }
    float4 r = {acc0 * inv, acc1 * inv, acc2 * inv, acc3 * inv};
    *(float4*)(orow + j) = r;
  }
}

extern "C" void kernel_launch(void* const* d_in, const int* in_sizes, int n_in,
                              void* d_out, int out_size, void* d_ws, size_t ws_size,
                              hipStream_t stream) {
  const float* x  = (const float*)d_in[0];
  const float* Wq = (const float*)d_in[1];
  const float* Wk = (const float*)d_in[2];
  const float* Wv = (const float*)d_in[3];
  const int* kmask = (const int*)d_in[4];
  char* ws = (char*)d_ws;
  u16* wt = (u16*)(ws + 33554432);            // 768 KB: Wt (dead after k_proj)
  u16* qb = (u16*)(ws + 34340864);            // 4 MB: Q bf16
  u16* kb = (u16*)(ws + 38535168);            // 4 MB: K bf16
  u16* vt = (u16*)(ws + 42729472);            // 4 MB: V^T bf16 [4][128][4096]
  u16* po = (u16*)ws;                         // 18.9 MB partial O (bf16)
  float* pl = (float*)(ws + 31195136);        // 295 KB partial l (po-region tail)
  float* out = (float*)d_out;

  k_wt<<<1536, 256, 0, stream>>>(Wq, Wk, Wv, wt);
  k_proj<<<256, 512, 0, stream>>>(x, wt, qb, kb, vt);
  k_attn<<<dim3(NCHUNK, 4), 512, 0, stream>>>(qb, kb, vt, kmask, po, pl);
  k_merge<<<dim3(32, 4), 256, 0, stream>>>(po, pl, out);
}